// Round 11
// baseline (175.525 us; speedup 1.0000x reference)
//
#include <hip/hip_runtime.h>
#include <stdint.h>

// Problem constants (fixed by the reference)
#define NV    8192   // variables
#define NC    4096   // checks
#define DC    6      // edges per check
#define DV    3      // edges per variable
#define NE    24576  // edges
#define NITER 5
#define BATCH 2048

// ---------------------------------------------------------------------------
// Setup 1: per-var edge lists (sorted ascending so the np.add.at association
// and slot ranks are deterministic).
// ---------------------------------------------------------------------------

__global__ void build_v2e(const int* __restrict__ cols, int* __restrict__ cnt,
                          unsigned short* __restrict__ v2e_tmp) {
  int e = blockIdx.x * blockDim.x + threadIdx.x;
  if (e >= NE) return;
  int v = cols[e];
  int s = atomicAdd(&cnt[v], 1);
  v2e_tmp[v * DV + s] = (unsigned short)e;
}

// Setup 2: per-edge slot codes, contiguous per check: cslot[e] = k*NV + v,
// where k = rank of edge e among its var's ascending edges. (e = c*6 + j.)
__global__ void invert_slots(const unsigned short* __restrict__ v2e_tmp,
                             unsigned short* __restrict__ cslot) {
  int v = blockIdx.x * blockDim.x + threadIdx.x;
  if (v >= NV) return;
  int a = v2e_tmp[v * 3 + 0];
  int b = v2e_tmp[v * 3 + 1];
  int c = v2e_tmp[v * 3 + 2];
  int t;
  if (a > b) { t = a; a = b; b = t; }
  if (b > c) { t = b; b = c; c = t; }
  if (a > b) { t = a; a = b; b = t; }
  cslot[a] = (unsigned short)(0 * NV + v);
  cslot[b] = (unsigned short)(1 * NV + v);
  cslot[c] = (unsigned short)(2 * NV + v);
}

// ---------------------------------------------------------------------------
// Setup 3: WAVE-granular bank schedule. One scheduler block per decode-wave
// (16 blocks, 64 lanes). Lane l owns decode checks {r*1024 + wid*64 + l}.
// NEW freedom vs R8: each lane CHOOSES which of its 4 checks enters each of
// the 4 sequential row-blocks (hardest-remaining-first via live per-quarter
// remaining-degree grem), so heavy banks spread over 24 rows, not 6.
// Then per block: R8's auction (hardest-first strict claim by this block's
// candidate histogram, relaxed fallback, one swap pass).
// Decode reads slotp positionally; c2v slots are keyed by edge, so ANY
// check->position assignment and edge order is BIT-EXACT (order-symmetric
// check update). Scheduler races never affect d_out.
// ---------------------------------------------------------------------------

__device__ __forceinline__ int qc(int n) { return (n > 1) ? (n - 1) : 0; }

__global__ __launch_bounds__(64) void wave_schedule(
    const unsigned short* __restrict__ cslot, unsigned int* __restrict__ slotp) {
  __shared__ int grem[4][32];     // quarter, bank: remaining candidate degree
  __shared__ int bq[4][32];       // this row-block's candidate histogram
  __shared__ int cnt[6][4][32];   // row, quarter, bank occupancy

  const int l = threadIdx.x;
  const int q = l >> 4;
  const int wid = blockIdx.x;     // 0..15

  // Load the 4 owned checks' slot codes.
  unsigned short sl[4][6];
  int bank[4][6];
  const unsigned int* cs32 = (const unsigned int*)cslot;
#pragma unroll
  for (int r = 0; r < 4; ++r) {
    int c = r * 1024 + wid * 64 + l;
    unsigned int a0 = cs32[c * 3 + 0];
    unsigned int a1 = cs32[c * 3 + 1];
    unsigned int a2 = cs32[c * 3 + 2];
    sl[r][0] = (unsigned short)(a0 & 0xffffu); sl[r][1] = (unsigned short)(a0 >> 16);
    sl[r][2] = (unsigned short)(a1 & 0xffffu); sl[r][3] = (unsigned short)(a1 >> 16);
    sl[r][4] = (unsigned short)(a2 & 0xffffu); sl[r][5] = (unsigned short)(a2 >> 16);
#pragma unroll
    for (int k = 0; k < 6; ++k) bank[r][k] = sl[r][k] & 31;
  }

  for (int t = l; t < 128; t += 64) ((int*)grem)[t] = 0;
  __syncthreads();
#pragma unroll
  for (int r = 0; r < 4; ++r)
#pragma unroll
    for (int k = 0; k < 6; ++k) atomicAdd(&grem[q][bank[r][k]], 1);
  __syncthreads();

  unsigned int taken = 0;   // which of my 4 checks already assigned

  for (int t = 0; t < 4; ++t) {
    for (int i = l; i < 128; i += 64) ((int*)bq)[i] = 0;
    for (int i = l; i < 768; i += 64) ((int*)cnt)[i] = 0;
    __syncthreads();

    // ---- pick: hardest remaining check (max sum of grem over its banks) ---
    int best = 0, bs = -1;
#pragma unroll
    for (int r = 0; r < 4; ++r) {
      if (taken & (1u << r)) continue;
      int s = 0;
#pragma unroll
      for (int k = 0; k < 6; ++k) s += grem[q][bank[r][k]];
      if (s > bs) { bs = s; best = r; }
    }
    taken |= (1u << best);

    // Copy picked check into statically-indexed locals (avoid scratch).
    unsigned short msl[6];
    int mb[6];
#pragma unroll
    for (int k = 0; k < 6; ++k) {
      int vs = sl[0][k];
      if (best == 1) vs = sl[1][k];
      if (best == 2) vs = sl[2][k];
      if (best == 3) vs = sl[3][k];
      msl[k] = (unsigned short)vs;
      mb[k] = vs & 31;
    }
#pragma unroll
    for (int k = 0; k < 6; ++k) {
      atomicSub(&grem[q][mb[k]], 1);
      atomicAdd(&bq[q][mb[k]], 1);
    }
    __syncthreads();

    // ---- candidate order: this-block contention descending ----------------
    int key[6];
#pragma unroll
    for (int k = 0; k < 6; ++k) key[k] = (bq[q][mb[k]] << 3) | k;
#pragma unroll
    for (int i = 0; i < 5; ++i) {
#pragma unroll
      for (int j2 = 0; j2 < 5 - i; ++j2) {
        if (key[j2] < key[j2 + 1]) {
          int tt = key[j2]; key[j2] = key[j2 + 1]; key[j2 + 1] = tt;
        }
      }
    }

    // ---- strict auction over 6 rows, relaxed fallback ---------------------
    unsigned char perm[6];
    unsigned int used = 0;
    for (int j = 0; j < 6; ++j) {
      int placed = -1;
      for (int s = 0; s < 6; ++s) {
        int k = key[s] & 7;
        if (used & (1u << k)) continue;
        int bk = mb[k];
        if (cnt[j][q][bk] == 0) {
          if (atomicAdd(&cnt[j][q][bk], 1) == 0) { placed = k; break; }
          atomicSub(&cnt[j][q][bk], 1);
        }
      }
      if (placed < 0) {                  // relaxed: min-count unused candidate
        int bc = 1 << 30;
        for (int k = 0; k < 6; ++k) {
          if (used & (1u << k)) continue;
          int cc = cnt[j][q][mb[k]];
          if (cc < bc) { bc = cc; placed = k; }
        }
        atomicAdd(&cnt[j][q][mb[placed]], 1);
      }
      used |= (1u << placed);
      perm[j] = (unsigned char)placed;
      __syncthreads();
    }

    // ---- one swap-improvement pass ----------------------------------------
    for (int j1 = 0; j1 < 6; ++j1) {
      for (int j2 = j1 + 1; j2 < 6; ++j2) {
        int k1 = perm[j1], k2 = perm[j2];
        int b1 = mb[k1], b2 = mb[k2];
        if (b1 != b2) {
          int c11 = cnt[j1][q][b1], c12 = cnt[j1][q][b2];
          int c21 = cnt[j2][q][b1], c22 = cnt[j2][q][b2];
          int dOld = qc(c11) + qc(c12) + qc(c21) + qc(c22);
          int dNew = qc(c11 - 1) + qc(c12 + 1) + qc(c21 + 1) + qc(c22 - 1);
          if (dNew < dOld) {
            atomicSub(&cnt[j1][q][b1], 1); atomicAdd(&cnt[j1][q][b2], 1);
            atomicSub(&cnt[j2][q][b2], 1); atomicAdd(&cnt[j2][q][b1], 1);
            perm[j1] = (unsigned char)k2; perm[j2] = (unsigned char)k1;
          }
        }
        __syncthreads();
      }
    }

    // ---- emit this block's scheduled slot codes at position (t, wid, l) ---
    unsigned short pm[6];
#pragma unroll
    for (int j = 0; j < 6; ++j) pm[j] = msl[perm[j]];
    int cpos = t * 1024 + wid * 64 + l;
    slotp[0 * NC + cpos] = (unsigned int)pm[0] | ((unsigned int)pm[1] << 16);
    slotp[1 * NC + cpos] = (unsigned int)pm[2] | ((unsigned int)pm[3] << 16);
    slotp[2 * NC + cpos] = (unsigned int)pm[4] | ((unsigned int)pm[5] << 16);
    __syncthreads();
  }
}

// ---------------------------------------------------------------------------
// Fused decoder (R10-verbatim): one workgroup per batch element.
// LDS: 3 c2v planes (var-major, 96 KB) + 1 vl plane (32 KB) = 128 KB.
// c2v lives in the owning check-thread's REGISTERS across iterations.
// ---------------------------------------------------------------------------

__global__ __launch_bounds__(1024, 4) void decode_kernel(
    const float* __restrict__ ch, const float* __restrict__ wts,
    const unsigned int* __restrict__ slotp, float* __restrict__ out) {
  __shared__ float s_msg[NE];   // c2v planes, 96 KB
  __shared__ float s_vl[NV];    // var LLR plane, 32 KB

  const int tid = threadIdx.x;
  const int b = blockIdx.x;
  const float* chrow = ch + (size_t)b * NV;
  const float4* ch4 = (const float4*)chrow;

  float4 chreg[2];
  chreg[0] = ch4[tid];           // vars 4*tid .. 4*tid+3
  chreg[1] = ch4[1024 + tid];    // vars 4096+4*tid ..

  float w[NITER];
#pragma unroll
  for (int i = 0; i < NITER; ++i) w[i] = wts[i];

  // Preload slot indices (writes) and masked var indices (vl reads).
  int idx[4][6];
  int vidx[4][6];
#pragma unroll
  for (int r = 0; r < 4; ++r) {
    int c = tid + r * 1024;
    unsigned int p0 = slotp[c];
    unsigned int p1 = slotp[NC + c];
    unsigned int p2 = slotp[2 * NC + c];
    idx[r][0] = (int)(p0 & 0xFFFFu); idx[r][1] = (int)(p0 >> 16);
    idx[r][2] = (int)(p1 & 0xFFFFu); idx[r][3] = (int)(p1 >> 16);
    idx[r][4] = (int)(p2 & 0xFFFFu); idx[r][5] = (int)(p2 >> 16);
#pragma unroll
    for (int j = 0; j < 6; ++j) vidx[r][j] = idx[r][j] & (NV - 1);
  }

  // c2v for this thread's 4 checks, resident in registers across iterations.
  float creg[4][6];
#pragma unroll
  for (int r = 0; r < 4; ++r)
#pragma unroll
    for (int j = 0; j < 6; ++j) creg[r][j] = 0.0f;

  float4* m0 = (float4*)&s_msg[0];
  float4* m1 = (float4*)&s_msg[NV];
  float4* m2 = (float4*)&s_msg[2 * NV];
  float4* vl4 = (float4*)s_vl;

  // ---- init: vl = ch (it0 v2c = vl - 0 = ch) ------------------------------
#pragma unroll
  for (int p = 0; p < 2; ++p) vl4[p * 1024 + tid] = chreg[p];
  __syncthreads();

  for (int it = 0; it < NITER; ++it) {
    const float wi = w[it];

    // ---- Phase B: hoist ALL 24 vl reads (independent, pipelined) ----------
    float tv[4][6];
#pragma unroll
    for (int r = 0; r < 4; ++r)
#pragma unroll
      for (int j = 0; j < 6; ++j) tv[r][j] = s_vl[vidx[r][j]];

    // ---- Phase B compute + writes -----------------------------------------
#pragma unroll
    for (int r = 0; r < 4; ++r) {
      unsigned int u[6];
      float av[6];
      unsigned int xs = 0u;
#pragma unroll
      for (int j = 0; j < 6; ++j) {
        float t = tv[r][j] - creg[r][j];
        unsigned int uu = __float_as_uint(t);
        u[j] = uu;
        xs ^= uu;
        av[j] = __uint_as_float(uu & 0x7FFFFFFFu);
      }
      // 2-min tree: exact, order-independent (min3/med3/max)
      float m1a = fminf(fminf(av[0], av[1]), av[2]);
      float m1b = fminf(fminf(av[3], av[4]), av[5]);
      float meda = __builtin_amdgcn_fmed3f(av[0], av[1], av[2]);
      float medb = __builtin_amdgcn_fmed3f(av[3], av[4], av[5]);
      float m1v = fminf(m1a, m1b);
      float m2v = fminf(fminf(meda, medb), fmaxf(m1a, m1b));
      const bool anyz = (m1v == 0.0f);
      const float m1w = m1v * wi;
      const float m2w = m2v * wi;
#pragma unroll
      for (int j = 0; j < 6; ++j) {
        float mag = (av[j] == m1v) ? m2w : m1w;  // ties: m2v==m1v, matches ref
        unsigned int s = (xs ^ u[j]) & 0x80000000u;
        float o = __uint_as_float(__float_as_uint(mag) ^ s);
        if (anyz) o = 0.0f;
        creg[r][j] = o;
        s_msg[idx[r][j]] = o;
      }
    }
    __syncthreads();

    // ---- Phase A: vl = ch + ((c0+c1)+c2), one wide write ------------------
    if (it < NITER - 1) {
#pragma unroll
      for (int p = 0; p < 2; ++p) {
        int i4 = p * 1024 + tid;
        float4 c0 = m0[i4], c1 = m1[i4], c2 = m2[i4];
        float4 cr = chreg[p];
        float4 vl;
        vl.x = cr.x + ((c0.x + c1.x) + c2.x);   // np.add.at association
        vl.y = cr.y + ((c0.y + c1.y) + c2.y);
        vl.z = cr.z + ((c0.z + c1.z) + c2.z);
        vl.w = cr.w + ((c0.w + c1.w) + c2.w);
        vl4[i4] = vl;
      }
      __syncthreads();
    }
  }

  // ---- Final: out = ch + ((c0+c1)+c2), float4 stores ----------------------
  float4* orow4 = (float4*)(out + (size_t)b * NV);
#pragma unroll
  for (int p = 0; p < 2; ++p) {
    int i4 = p * 1024 + tid;
    float4 c0 = m0[i4], c1 = m1[i4], c2 = m2[i4];
    float4 cr = chreg[p];
    float4 o;
    o.x = cr.x + ((c0.x + c1.x) + c2.x);
    o.y = cr.y + ((c0.y + c1.y) + c2.y);
    o.z = cr.z + ((c0.z + c1.z) + c2.z);
    o.w = cr.w + ((c0.w + c1.w) + c2.w);
    orow4[i4] = o;
  }
}

// ---------------------------------------------------------------------------

extern "C" void kernel_launch(void* const* d_in, const int* in_sizes, int n_in,
                              void* d_out, int out_size, void* d_ws, size_t ws_size,
                              hipStream_t stream) {
  (void)in_sizes; (void)n_in; (void)out_size; (void)ws_size;

  const float* ch   = (const float*)d_in[0];   // [BATCH, NV] f32
  const float* wts  = (const float*)d_in[1];   // [NITER, 1] f32
  const int*  Hcols = (const int*)d_in[3];     // [NE] i32
  float* out = (float*)d_out;

  char* ws = (char*)d_ws;
  int*            cnt     = (int*)(ws + 0);                  // 32768 B
  unsigned short* v2e_tmp = (unsigned short*)(ws + 32768);   // 49152 B
  unsigned short* cslot   = (unsigned short*)(ws + 81920);   // 49152 B
  unsigned int*   slotp   = (unsigned int*)(ws + 131072);    // 49152 B
  // total ws use: 180224 B

  hipMemsetAsync(cnt, 0, NV * sizeof(int), stream);
  build_v2e<<<(NE + 255) / 256, 256, 0, stream>>>(Hcols, cnt, v2e_tmp);
  invert_slots<<<(NV + 255) / 256, 256, 0, stream>>>(v2e_tmp, cslot);
  wave_schedule<<<16, 64, 0, stream>>>(cslot, slotp);

  decode_kernel<<<BATCH, 1024, 0, stream>>>(ch, wts, slotp, out);
}